// Round 1
// baseline (1172.726 us; speedup 1.0000x reference)
//
#include <hip/hip_runtime.h>
#include <math.h>

// ---------------- wave helpers (wave = 64 lanes) ----------------
__device__ __forceinline__ float wave_sum(float v) {
#pragma unroll
  for (int off = 1; off < 64; off <<= 1) v += __shfl_xor(v, off);
  return v;
}
__device__ __forceinline__ float wave_max(float v) {
#pragma unroll
  for (int off = 1; off < 64; off <<= 1) v = fmaxf(v, __shfl_xor(v, off));
  return v;
}

// ---------------- CSR build ----------------
// edges e in [0, E): src = ei[e], dst = ei[E+e];  e in [E, E+N): self-loop e-E.
__global__ void histo_kernel(const int* __restrict__ ei, int E, int N,
                             int* __restrict__ counts) {
  int e = blockIdx.x * blockDim.x + threadIdx.x;
  int etot = E + N;
  if (e >= etot) return;
  int d = (e < E) ? ei[E + e] : (e - E);
  atomicAdd(&counts[d], 1);
}

__global__ void scan1_kernel(const int* __restrict__ counts, int* __restrict__ excl,
                             int* __restrict__ bsums, int N) {
  __shared__ int sm[256];
  int t = threadIdx.x;
  int i = blockIdx.x * 256 + t;
  int v = (i < N) ? counts[i] : 0;
  sm[t] = v;
  __syncthreads();
#pragma unroll
  for (int off = 1; off < 256; off <<= 1) {
    int add = (t >= off) ? sm[t - off] : 0;
    __syncthreads();
    sm[t] += add;
    __syncthreads();
  }
  if (i < N) excl[i] = sm[t] - v;
  if (t == 255) bsums[blockIdx.x] = sm[255];
}

__global__ void scan2_kernel(int* __restrict__ bsums, int nb) {
  __shared__ int sm[256];
  int t = threadIdx.x;
  int v = (t < nb) ? bsums[t] : 0;
  sm[t] = v;
  __syncthreads();
#pragma unroll
  for (int off = 1; off < 256; off <<= 1) {
    int add = (t >= off) ? sm[t - off] : 0;
    __syncthreads();
    sm[t] += add;
    __syncthreads();
  }
  if (t < nb) bsums[t] = sm[t] - v;  // exclusive
}

__global__ void scan3_kernel(const int* __restrict__ excl, const int* __restrict__ bsums,
                             int* __restrict__ rowptr, int* __restrict__ cursor,
                             int N, int etot) {
  int i = blockIdx.x * 256 + threadIdx.x;
  if (i < N) {
    int v = excl[i] + bsums[i >> 8];
    rowptr[i] = v;
    cursor[i] = v;
  }
  if (i == N) rowptr[N] = etot;
}

__global__ void scatter_kernel(const int* __restrict__ ei, int E, int N,
                               int* __restrict__ cursor, int* __restrict__ csr_src) {
  int e = blockIdx.x * blockDim.x + threadIdx.x;
  int etot = E + N;
  if (e >= etot) return;
  int s, d;
  if (e < E) { s = ei[e]; d = ei[E + e]; } else { s = e - E; d = e - E; }
  int pos = atomicAdd(&cursor[d], 1);
  csr_src[pos] = s;
}

// ---------------- GEMM: H = X(N x 128) @ W(128 x COLS), + hl/hr epilogue ----------
template <int COLS>
__global__ __launch_bounds__(256) void gemm_kernel(
    const float* __restrict__ X, const float* __restrict__ W,
    const float* __restrict__ al, const float* __restrict__ ar,
    float* __restrict__ H, float* __restrict__ hl, float* __restrict__ hr, int N) {
  __shared__ float Wl[128 * COLS];
  const int tid = threadIdx.x;
  constexpr int WELEM = 128 * COLS;
  for (int i = tid * 4; i < WELEM; i += 256 * 4) {
    *(float4*)&Wl[i] = *(const float4*)&W[i];
  }
  __syncthreads();
  const int wave = tid >> 6, lane = tid & 63;
  const int ROWS_PER_WAVE = 8;
  int row0 = (blockIdx.x * 4 + wave) * ROWS_PER_WAVE;
  int rend = row0 + ROWS_PER_WAVE;
  if (rend > N) rend = N;
  for (int r = row0; r < rend; ++r) {
    float acc0 = 0.f, acc1 = 0.f;
    const float* xr = X + (size_t)r * 128;
#pragma unroll
    for (int k = 0; k < 128; ++k) {
      float xk = xr[k];
      acc0 = fmaf(xk, Wl[k * COLS + lane], acc0);
      if (COLS == 128) acc1 = fmaf(xk, Wl[k * COLS + 64 + lane], acc1);
    }
    H[(size_t)r * COLS + lane] = acc0;
    if (COLS == 128) H[(size_t)r * COLS + 64 + lane] = acc1;
    float pl = acc0 * al[lane];
    float pr = acc0 * ar[lane];
    if (COLS == 128) {
      pl = fmaf(acc1, al[64 + lane], pl);
      pr = fmaf(acc1, ar[64 + lane], pr);
    }
    pl = wave_sum(pl);
    pr = wave_sum(pr);
    if (lane == 0) {
      hl[r] = pl;
      hr[r] = pr;
    }
  }
}

// ---------------- per-node attention + aggregation ----------------
// one wave per destination node
template <int COLS, bool LAST>
__global__ __launch_bounds__(256) void node_kernel(
    const float* __restrict__ H, const float* __restrict__ hl,
    const float* __restrict__ hr, const int* __restrict__ rowptr,
    const int* __restrict__ csr_src, const float* __restrict__ b,
    float* __restrict__ OUT, int N) {
  int node = blockIdx.x * 4 + (threadIdx.x >> 6);
  if (node >= N) return;
  int lane = threadIdx.x & 63;

  const float hi0 = H[(size_t)node * COLS + lane];
  const float hi1 = (COLS == 128) ? H[(size_t)node * COLS + 64 + lane] : 0.f;
  const int start = rowptr[node], end = rowptr[node + 1];
  const float hri = hr[node];

  // pass 1: max of alpha
  float amax = -INFINITY;
  for (int e = start; e < end; ++e) {
    int s = csr_src[e];
    float d = hi0 * H[(size_t)s * COLS + lane];
    if (COLS == 128) d = fmaf(hi1, H[(size_t)s * COLS + 64 + lane], d);
    float logit = wave_sum(d);
    float gate = 1.f / (1.f + __expf(-logit));
    float a = (hl[s] + hri) * gate;
    a = (a >= 0.f) ? a : 0.2f * a;
    amax = fmaxf(amax, a);
  }

  // pass 2: recompute alpha (bit-identical), accumulate
  float acc0 = 0.f, acc1 = 0.f, sumw = 0.f;
  for (int e = start; e < end; ++e) {
    int s = csr_src[e];
    float h0 = H[(size_t)s * COLS + lane];
    float h1 = (COLS == 128) ? H[(size_t)s * COLS + 64 + lane] : 0.f;
    float d = hi0 * h0;
    if (COLS == 128) d = fmaf(hi1, h1, d);
    float logit = wave_sum(d);
    float gate = 1.f / (1.f + __expf(-logit));
    float a = (hl[s] + hri) * gate;
    a = (a >= 0.f) ? a : 0.2f * a;
    float w = __expf(a - amax);
    sumw += w;
    acc0 = fmaf(w, h0, acc0);
    if (COLS == 128) acc1 = fmaf(w, h1, acc1);
  }

  float inv = 1.f / (sumw + 1e-16f);
  float o0 = fmaxf(fmaf(acc0, inv, 0.f) + b[lane], 0.f);  // + bias, relu
  if (LAST) {
    // COLS == 64: one value per lane -> log_softmax across the wave
    float m = wave_max(o0);
    float ex = __expf(o0 - m);
    float se = wave_sum(ex);
    OUT[(size_t)node * 64 + lane] = o0 - m - logf(se);
  } else {
    OUT[(size_t)node * COLS + lane] = o0;
    if (COLS == 128) {
      float o1 = fmaxf(acc1 * inv + b[64 + lane], 0.f);
      OUT[(size_t)node * COLS + 64 + lane] = o1;
    }
  }
}

// ---------------- launch ----------------
extern "C" void kernel_launch(void* const* d_in, const int* in_sizes, int n_in,
                              void* d_out, int out_size, void* d_ws, size_t ws_size,
                              hipStream_t stream) {
  const float* x = (const float*)d_in[0];
  const int* ei = (const int*)d_in[1];
  const float* W0 = (const float*)d_in[2];
  const float* al0 = (const float*)d_in[3];
  const float* ar0 = (const float*)d_in[4];
  const float* b0 = (const float*)d_in[5];
  const float* W1 = (const float*)d_in[6];
  const float* al1 = (const float*)d_in[7];
  const float* ar1 = (const float*)d_in[8];
  const float* b1 = (const float*)d_in[9];
  const float* W2 = (const float*)d_in[10];
  const float* al2 = (const float*)d_in[11];
  const float* ar2 = (const float*)d_in[12];
  const float* b2 = (const float*)d_in[13];

  const int N = in_sizes[0] / 128;  // 50000
  const int E = in_sizes[1] / 2;    // 640000
  const int ETOT = E + N;

  // workspace carve-up (256B aligned)
  char* p = (char*)d_ws;
  auto carve = [&](size_t bytes) {
    void* r = (void*)p;
    p += (bytes + 255) & ~(size_t)255;
    return r;
  };
  float* hA = (float*)carve((size_t)N * 128 * sizeof(float));
  float* hB = (float*)carve((size_t)N * 128 * sizeof(float));
  float* hl = (float*)carve((size_t)N * sizeof(float));
  float* hr = (float*)carve((size_t)N * sizeof(float));
  int* counts = (int*)carve((size_t)N * sizeof(int));
  int* excl = (int*)carve((size_t)N * sizeof(int));
  int* bsums = (int*)carve(1024 * sizeof(int));
  int* rowptr = (int*)carve((size_t)(N + 1) * sizeof(int));
  int* cursor = (int*)carve((size_t)(N + 1) * sizeof(int));
  int* csr_src = (int*)carve((size_t)ETOT * sizeof(int));

  // ---- CSR build ----
  hipMemsetAsync(counts, 0, (size_t)N * sizeof(int), stream);
  {
    int nb = (ETOT + 255) / 256;
    histo_kernel<<<nb, 256, 0, stream>>>(ei, E, N, counts);
  }
  int nbs = (N + 255) / 256;  // 196 <= 256
  scan1_kernel<<<nbs, 256, 0, stream>>>(counts, excl, bsums, N);
  scan2_kernel<<<1, 256, 0, stream>>>(bsums, nbs);
  scan3_kernel<<<(N + 256) / 256 + 1, 256, 0, stream>>>(excl, bsums, rowptr, cursor, N, ETOT);
  {
    int nb = (ETOT + 255) / 256;
    scatter_kernel<<<nb, 256, 0, stream>>>(ei, E, N, cursor, csr_src);
  }

  const int gemm_grid = (N + 31) / 32;  // 32 rows per block (4 waves x 8 rows)
  const int node_grid = (N + 3) / 4;    // 4 nodes per block (1 wave each)

  // ---- layer 0: x -> hA -> hB ----
  gemm_kernel<128><<<gemm_grid, 256, 0, stream>>>(x, W0, al0, ar0, hA, hl, hr, N);
  node_kernel<128, false><<<node_grid, 256, 0, stream>>>(hA, hl, hr, rowptr, csr_src, b0, hB, N);

  // ---- layer 1: hB -> hA -> hB ----
  gemm_kernel<128><<<gemm_grid, 256, 0, stream>>>(hB, W1, al1, ar1, hA, hl, hr, N);
  node_kernel<128, false><<<node_grid, 256, 0, stream>>>(hA, hl, hr, rowptr, csr_src, b1, hB, N);

  // ---- layer 2: hB -> hA(64) -> d_out ----
  gemm_kernel<64><<<gemm_grid, 256, 0, stream>>>(hB, W2, al2, ar2, hA, hl, hr, N);
  node_kernel<64, true><<<node_grid, 256, 0, stream>>>(hA, hl, hr, rowptr, csr_src, b2,
                                                       (float*)d_out, N);
}

// Round 2
// 426.065 us; speedup vs baseline: 2.7525x; 2.7525x over previous
//
#include <hip/hip_runtime.h>
#include <math.h>

// ---------------- wave helpers (wave = 64 lanes) ----------------
__device__ __forceinline__ float wave_sum(float v) {
#pragma unroll
  for (int off = 1; off < 64; off <<= 1) v += __shfl_xor(v, off);
  return v;
}
__device__ __forceinline__ float wave_max(float v) {
#pragma unroll
  for (int off = 1; off < 64; off <<= 1) v = fmaxf(v, __shfl_xor(v, off));
  return v;
}
__device__ __forceinline__ float f4c(const float4& v, int t) {
  return t == 0 ? v.x : t == 1 ? v.y : t == 2 ? v.z : v.w;
}

// ---------------- CSR build ----------------
__global__ void histo_kernel(const int* __restrict__ ei, int E, int N,
                             int* __restrict__ counts) {
  int e = blockIdx.x * blockDim.x + threadIdx.x;
  int etot = E + N;
  if (e >= etot) return;
  int d = (e < E) ? ei[E + e] : (e - E);
  atomicAdd(&counts[d], 1);
}

__global__ void scan1_kernel(const int* __restrict__ counts, int* __restrict__ excl,
                             int* __restrict__ bsums, int N) {
  __shared__ int sm[256];
  int t = threadIdx.x;
  int i = blockIdx.x * 256 + t;
  int v = (i < N) ? counts[i] : 0;
  sm[t] = v;
  __syncthreads();
#pragma unroll
  for (int off = 1; off < 256; off <<= 1) {
    int add = (t >= off) ? sm[t - off] : 0;
    __syncthreads();
    sm[t] += add;
    __syncthreads();
  }
  if (i < N) excl[i] = sm[t] - v;
  if (t == 255) bsums[blockIdx.x] = sm[255];
}

__global__ void scan2_kernel(int* __restrict__ bsums, int nb) {
  __shared__ int sm[256];
  int t = threadIdx.x;
  int v = (t < nb) ? bsums[t] : 0;
  sm[t] = v;
  __syncthreads();
#pragma unroll
  for (int off = 1; off < 256; off <<= 1) {
    int add = (t >= off) ? sm[t - off] : 0;
    __syncthreads();
    sm[t] += add;
    __syncthreads();
  }
  if (t < nb) bsums[t] = sm[t] - v;  // exclusive
}

__global__ void scan3_kernel(const int* __restrict__ excl, const int* __restrict__ bsums,
                             int* __restrict__ rowptr, int* __restrict__ cursor,
                             int N, int etot) {
  int i = blockIdx.x * 256 + threadIdx.x;
  if (i < N) {
    int v = excl[i] + bsums[i >> 8];
    rowptr[i] = v;
    cursor[i] = v;
  }
  if (i == N) rowptr[N] = etot;
}

__global__ void scatter_kernel(const int* __restrict__ ei, int E, int N,
                               int* __restrict__ cursor, int* __restrict__ csr_src) {
  int e = blockIdx.x * blockDim.x + threadIdx.x;
  int etot = E + N;
  if (e >= etot) return;
  int s, d;
  if (e < E) { s = ei[e]; d = ei[E + e]; } else { s = e - E; d = e - E; }
  int pos = atomicAdd(&cursor[d], 1);
  csr_src[pos] = s;
}

// ---------------- GEMM: H = X(N x 128) @ W(128 x COLS) + hl/hr epilogue -------
// Block: 256 threads, 64 rows x COLS. Thread (tx=tid&15, ty=tid>>4) owns
// rows r0+ty*4..+3, cols {tx*4..+3} and (COLS==128) {64+tx*4..+3}.
template <int COLS>
__global__ __launch_bounds__(256) void gemm_kernel(
    const float* __restrict__ X, const float* __restrict__ W,
    const float* __restrict__ al, const float* __restrict__ ar,
    float* __restrict__ H, float* __restrict__ hl, float* __restrict__ hr, int N) {
  constexpr int KC = 64;       // K-chunk
  constexpr int XS = KC + 4;   // padded X row stride (floats): 68 -> 2-way bank alias (free)
  __shared__ float Ws[KC * COLS];
  __shared__ float Xs[64 * XS];
  const int tid = threadIdx.x;
  const int tx = tid & 15, ty = tid >> 4;
  const int r0 = blockIdx.x * 64;

  float acc[4][2][4];
#pragma unroll
  for (int i = 0; i < 4; ++i)
#pragma unroll
    for (int h = 0; h < 2; ++h)
#pragma unroll
      for (int j = 0; j < 4; ++j) acc[i][h][j] = 0.f;

  for (int k0 = 0; k0 < 128; k0 += KC) {
    __syncthreads();
    // stage W chunk (contiguous KC*COLS floats)
    constexpr int WQ = KC * COLS / 4;
    const float4* wg = (const float4*)(W + k0 * COLS);
#pragma unroll
    for (int i = tid; i < WQ; i += 256) ((float4*)Ws)[i] = wg[i];
    // stage X chunk: 64 rows x KC floats
#pragma unroll
    for (int i = tid; i < 64 * KC / 4; i += 256) {
      int row = i >> 4;   // KC/4 = 16 float4 per row
      int kq = i & 15;
      int gr = r0 + row;
      if (gr > N - 1) gr = N - 1;
      float4 v = *(const float4*)(X + (size_t)gr * 128 + k0 + kq * 4);
      *(float4*)(&Xs[row * XS + kq * 4]) = v;
    }
    __syncthreads();
    // compute
#pragma unroll
    for (int kk0 = 0; kk0 < KC; kk0 += 4) {
      float4 xv[4];
#pragma unroll
      for (int i = 0; i < 4; ++i)
        xv[i] = *(const float4*)(&Xs[(ty * 4 + i) * XS + kk0]);
#pragma unroll
      for (int t = 0; t < 4; ++t) {
        float4 w0 = *(const float4*)(&Ws[(kk0 + t) * COLS + tx * 4]);
        float4 w1;
        if constexpr (COLS == 128) w1 = *(const float4*)(&Ws[(kk0 + t) * COLS + 64 + tx * 4]);
#pragma unroll
        for (int i = 0; i < 4; ++i) {
          float xk = f4c(xv[i], t);
          acc[i][0][0] = fmaf(xk, w0.x, acc[i][0][0]);
          acc[i][0][1] = fmaf(xk, w0.y, acc[i][0][1]);
          acc[i][0][2] = fmaf(xk, w0.z, acc[i][0][2]);
          acc[i][0][3] = fmaf(xk, w0.w, acc[i][0][3]);
          if constexpr (COLS == 128) {
            acc[i][1][0] = fmaf(xk, w1.x, acc[i][1][0]);
            acc[i][1][1] = fmaf(xk, w1.y, acc[i][1][1]);
            acc[i][1][2] = fmaf(xk, w1.z, acc[i][1][2]);
            acc[i][1][3] = fmaf(xk, w1.w, acc[i][1][3]);
          }
        }
      }
    }
  }

  // epilogue: store H, fused hl/hr
  float4 alv0 = *(const float4*)(al + tx * 4);
  float4 arv0 = *(const float4*)(ar + tx * 4);
  float4 alv1, arv1;
  if constexpr (COLS == 128) {
    alv1 = *(const float4*)(al + 64 + tx * 4);
    arv1 = *(const float4*)(ar + 64 + tx * 4);
  }
#pragma unroll
  for (int i = 0; i < 4; ++i) {
    int r = r0 + ty * 4 + i;
    bool ok = r < N;
    float4 o0 = make_float4(acc[i][0][0], acc[i][0][1], acc[i][0][2], acc[i][0][3]);
    float pl = o0.x * alv0.x + o0.y * alv0.y + o0.z * alv0.z + o0.w * alv0.w;
    float pr = o0.x * arv0.x + o0.y * arv0.y + o0.z * arv0.z + o0.w * arv0.w;
    if (ok) *(float4*)(&H[(size_t)r * COLS + tx * 4]) = o0;
    if constexpr (COLS == 128) {
      float4 o1 = make_float4(acc[i][1][0], acc[i][1][1], acc[i][1][2], acc[i][1][3]);
      pl += o1.x * alv1.x + o1.y * alv1.y + o1.z * alv1.z + o1.w * alv1.w;
      pr += o1.x * arv1.x + o1.y * arv1.y + o1.z * arv1.z + o1.w * arv1.w;
      if (ok) *(float4*)(&H[(size_t)r * COLS + 64 + tx * 4]) = o1;
    }
#pragma unroll
    for (int off = 1; off < 16; off <<= 1) {
      pl += __shfl_xor(pl, off);
      pr += __shfl_xor(pr, off);
    }
    if (ok && tx == 0) {
      hl[r] = pl;
      hr[r] = pr;
    }
  }
}

// ---------------- per-node attention + aggregation (online softmax) ----------
// one wave per destination node; alpha is wave-uniform so the rescale branch
// is non-divergent.
template <int COLS, bool LAST>
__global__ __launch_bounds__(256) void node_kernel(
    const float* __restrict__ H, const float* __restrict__ hl,
    const float* __restrict__ hr, const int* __restrict__ rowptr,
    const int* __restrict__ csr_src, const float* __restrict__ b,
    float* __restrict__ OUT, int N) {
  int node = blockIdx.x * 4 + (threadIdx.x >> 6);
  if (node >= N) return;
  int lane = threadIdx.x & 63;

  const float hi0 = H[(size_t)node * COLS + lane];
  float hi1 = 0.f;
  if constexpr (COLS == 128) hi1 = H[(size_t)node * COLS + 64 + lane];
  const int start = rowptr[node], end = rowptr[node + 1];
  const float hri = hr[node];

  float m = -INFINITY, sumw = 0.f, acc0 = 0.f, acc1 = 0.f;
  // 1-deep software prefetch (every node has >=1 edge: self-loop)
  int s = csr_src[start];
  float h0 = H[(size_t)s * COLS + lane];
  float h1 = 0.f;
  if constexpr (COLS == 128) h1 = H[(size_t)s * COLS + 64 + lane];
  float hls = hl[s];

  for (int e = start; e < end; ++e) {
    float ch0 = h0, ch1 = h1, chl = hls;
    if (e + 1 < end) {
      s = csr_src[e + 1];
      h0 = H[(size_t)s * COLS + lane];
      if constexpr (COLS == 128) h1 = H[(size_t)s * COLS + 64 + lane];
      hls = hl[s];
    }
    float d = hi0 * ch0;
    if constexpr (COLS == 128) d = fmaf(hi1, ch1, d);
    float logit = wave_sum(d);
    float gate = 1.f / (1.f + __expf(-logit));
    float a = (chl + hri) * gate;
    a = (a >= 0.f) ? a : 0.2f * a;
    if (a > m) {                     // wave-uniform branch
      float sc = __expf(m - a);      // first iter: exp(-inf) = 0
      sumw *= sc;
      acc0 *= sc;
      acc1 *= sc;
      m = a;
    }
    float w = __expf(a - m);
    sumw += w;
    acc0 = fmaf(w, ch0, acc0);
    if constexpr (COLS == 128) acc1 = fmaf(w, ch1, acc1);
  }

  float inv = 1.f / (sumw + 1e-16f);
  float o0 = fmaxf(acc0 * inv + b[lane], 0.f);  // + bias, relu
  if constexpr (LAST) {
    // COLS == 64: one value per lane -> log_softmax across the wave
    float mm = wave_max(o0);
    float ex = __expf(o0 - mm);
    float se = wave_sum(ex);
    OUT[(size_t)node * 64 + lane] = o0 - mm - logf(se);
  } else {
    OUT[(size_t)node * COLS + lane] = o0;
    if constexpr (COLS == 128) {
      float o1 = fmaxf(acc1 * inv + b[64 + lane], 0.f);
      OUT[(size_t)node * COLS + 64 + lane] = o1;
    }
  }
}

// ---------------- launch ----------------
extern "C" void kernel_launch(void* const* d_in, const int* in_sizes, int n_in,
                              void* d_out, int out_size, void* d_ws, size_t ws_size,
                              hipStream_t stream) {
  const float* x = (const float*)d_in[0];
  const int* ei = (const int*)d_in[1];
  const float* W0 = (const float*)d_in[2];
  const float* al0 = (const float*)d_in[3];
  const float* ar0 = (const float*)d_in[4];
  const float* b0 = (const float*)d_in[5];
  const float* W1 = (const float*)d_in[6];
  const float* al1 = (const float*)d_in[7];
  const float* ar1 = (const float*)d_in[8];
  const float* b1 = (const float*)d_in[9];
  const float* W2 = (const float*)d_in[10];
  const float* al2 = (const float*)d_in[11];
  const float* ar2 = (const float*)d_in[12];
  const float* b2 = (const float*)d_in[13];

  const int N = in_sizes[0] / 128;  // 50000
  const int E = in_sizes[1] / 2;    // 640000
  const int ETOT = E + N;

  char* p = (char*)d_ws;
  auto carve = [&](size_t bytes) {
    void* r = (void*)p;
    p += (bytes + 255) & ~(size_t)255;
    return r;
  };
  float* hA = (float*)carve((size_t)N * 128 * sizeof(float));
  float* hB = (float*)carve((size_t)N * 128 * sizeof(float));
  float* hl = (float*)carve((size_t)N * sizeof(float));
  float* hr = (float*)carve((size_t)N * sizeof(float));
  int* counts = (int*)carve((size_t)N * sizeof(int));
  int* excl = (int*)carve((size_t)N * sizeof(int));
  int* bsums = (int*)carve(1024 * sizeof(int));
  int* rowptr = (int*)carve((size_t)(N + 1) * sizeof(int));
  int* cursor = (int*)carve((size_t)(N + 1) * sizeof(int));
  int* csr_src = (int*)carve((size_t)ETOT * sizeof(int));

  // ---- CSR build ----
  hipMemsetAsync(counts, 0, (size_t)N * sizeof(int), stream);
  {
    int nb = (ETOT + 255) / 256;
    histo_kernel<<<nb, 256, 0, stream>>>(ei, E, N, counts);
  }
  int nbs = (N + 255) / 256;
  scan1_kernel<<<nbs, 256, 0, stream>>>(counts, excl, bsums, N);
  scan2_kernel<<<1, 256, 0, stream>>>(bsums, nbs);
  scan3_kernel<<<(N + 256) / 256 + 1, 256, 0, stream>>>(excl, bsums, rowptr, cursor, N, ETOT);
  {
    int nb = (ETOT + 255) / 256;
    scatter_kernel<<<nb, 256, 0, stream>>>(ei, E, N, cursor, csr_src);
  }

  const int gemm_grid = (N + 63) / 64;
  const int node_grid = (N + 3) / 4;

  // ---- layer 0 ----
  gemm_kernel<128><<<gemm_grid, 256, 0, stream>>>(x, W0, al0, ar0, hA, hl, hr, N);
  node_kernel<128, false><<<node_grid, 256, 0, stream>>>(hA, hl, hr, rowptr, csr_src, b0, hB, N);

  // ---- layer 1 ----
  gemm_kernel<128><<<gemm_grid, 256, 0, stream>>>(hB, W1, al1, ar1, hA, hl, hr, N);
  node_kernel<128, false><<<node_grid, 256, 0, stream>>>(hA, hl, hr, rowptr, csr_src, b1, hB, N);

  // ---- layer 2 ----
  gemm_kernel<64><<<gemm_grid, 256, 0, stream>>>(hB, W2, al2, ar2, hA, hl, hr, N);
  node_kernel<64, true><<<node_grid, 256, 0, stream>>>(hA, hl, hr, rowptr, csr_src, b2,
                                                       (float*)d_out, N);
}

// Round 3
// 319.700 us; speedup vs baseline: 3.6682x; 1.3327x over previous
//
#include <hip/hip_runtime.h>
#include <math.h>

// ---------------- wave helpers (wave = 64 lanes) ----------------
__device__ __forceinline__ float wave_sum(float v) {
#pragma unroll
  for (int off = 1; off < 64; off <<= 1) v += __shfl_xor(v, off);
  return v;
}
__device__ __forceinline__ float f4c(const float4& v, int t) {
  return t == 0 ? v.x : t == 1 ? v.y : t == 2 ? v.z : v.w;
}

// ---------------- CSR build ----------------
__global__ void histo_kernel(const int* __restrict__ ei, int E, int N,
                             int* __restrict__ counts) {
  int e = blockIdx.x * blockDim.x + threadIdx.x;
  int etot = E + N;
  if (e >= etot) return;
  int d = (e < E) ? ei[E + e] : (e - E);
  atomicAdd(&counts[d], 1);
}

__global__ void scan1_kernel(const int* __restrict__ counts, int* __restrict__ excl,
                             int* __restrict__ bsums, int N) {
  __shared__ int sm[256];
  int t = threadIdx.x;
  int i = blockIdx.x * 256 + t;
  int v = (i < N) ? counts[i] : 0;
  sm[t] = v;
  __syncthreads();
#pragma unroll
  for (int off = 1; off < 256; off <<= 1) {
    int add = (t >= off) ? sm[t - off] : 0;
    __syncthreads();
    sm[t] += add;
    __syncthreads();
  }
  if (i < N) excl[i] = sm[t] - v;
  if (t == 255) bsums[blockIdx.x] = sm[255];
}

__global__ void scan2_kernel(int* __restrict__ bsums, int nb) {
  __shared__ int sm[256];
  int t = threadIdx.x;
  int v = (t < nb) ? bsums[t] : 0;
  sm[t] = v;
  __syncthreads();
#pragma unroll
  for (int off = 1; off < 256; off <<= 1) {
    int add = (t >= off) ? sm[t - off] : 0;
    __syncthreads();
    sm[t] += add;
    __syncthreads();
  }
  if (t < nb) bsums[t] = sm[t] - v;  // exclusive
}

__global__ void scan3_kernel(const int* __restrict__ excl, const int* __restrict__ bsums,
                             int* __restrict__ rowptr, int* __restrict__ cursor,
                             int N, int etot) {
  int i = blockIdx.x * 256 + threadIdx.x;
  if (i < N) {
    int v = excl[i] + bsums[i >> 8];
    rowptr[i] = v;
    cursor[i] = v;
  }
  if (i == N) rowptr[N] = etot;
}

__global__ void scatter_kernel(const int* __restrict__ ei, int E, int N,
                               int* __restrict__ cursor, int* __restrict__ csr_src) {
  int e = blockIdx.x * blockDim.x + threadIdx.x;
  int etot = E + N;
  if (e >= etot) return;
  int s, d;
  if (e < E) { s = ei[e]; d = ei[E + e]; } else { s = e - E; d = e - E; }
  int pos = atomicAdd(&cursor[d], 1);
  csr_src[pos] = s;
}

// ---------------- GEMM: H = X(N x 128) @ W(128 x COLS) + hl/hr epilogue -------
template <int COLS>
__global__ __launch_bounds__(256) void gemm_kernel(
    const float* __restrict__ X, const float* __restrict__ W,
    const float* __restrict__ al, const float* __restrict__ ar,
    float* __restrict__ H, float* __restrict__ hl, float* __restrict__ hr, int N) {
  constexpr int KC = 64;       // K-chunk
  constexpr int XS = KC + 4;   // padded X row stride: 2-way bank alias (free)
  __shared__ float Ws[KC * COLS];
  __shared__ float Xs[64 * XS];
  const int tid = threadIdx.x;
  const int tx = tid & 15, ty = tid >> 4;
  const int r0 = blockIdx.x * 64;

  float acc[4][2][4];
#pragma unroll
  for (int i = 0; i < 4; ++i)
#pragma unroll
    for (int h = 0; h < 2; ++h)
#pragma unroll
      for (int j = 0; j < 4; ++j) acc[i][h][j] = 0.f;

  for (int k0 = 0; k0 < 128; k0 += KC) {
    __syncthreads();
    constexpr int WQ = KC * COLS / 4;
    const float4* wg = (const float4*)(W + k0 * COLS);
#pragma unroll
    for (int i = tid; i < WQ; i += 256) ((float4*)Ws)[i] = wg[i];
#pragma unroll
    for (int i = tid; i < 64 * KC / 4; i += 256) {
      int row = i >> 4;
      int kq = i & 15;
      int gr = r0 + row;
      if (gr > N - 1) gr = N - 1;
      float4 v = *(const float4*)(X + (size_t)gr * 128 + k0 + kq * 4);
      *(float4*)(&Xs[row * XS + kq * 4]) = v;
    }
    __syncthreads();
#pragma unroll
    for (int kk0 = 0; kk0 < KC; kk0 += 4) {
      float4 xv[4];
#pragma unroll
      for (int i = 0; i < 4; ++i)
        xv[i] = *(const float4*)(&Xs[(ty * 4 + i) * XS + kk0]);
#pragma unroll
      for (int t = 0; t < 4; ++t) {
        float4 w0 = *(const float4*)(&Ws[(kk0 + t) * COLS + tx * 4]);
        float4 w1;
        if constexpr (COLS == 128) w1 = *(const float4*)(&Ws[(kk0 + t) * COLS + 64 + tx * 4]);
#pragma unroll
        for (int i = 0; i < 4; ++i) {
          float xk = f4c(xv[i], t);
          acc[i][0][0] = fmaf(xk, w0.x, acc[i][0][0]);
          acc[i][0][1] = fmaf(xk, w0.y, acc[i][0][1]);
          acc[i][0][2] = fmaf(xk, w0.z, acc[i][0][2]);
          acc[i][0][3] = fmaf(xk, w0.w, acc[i][0][3]);
          if constexpr (COLS == 128) {
            acc[i][1][0] = fmaf(xk, w1.x, acc[i][1][0]);
            acc[i][1][1] = fmaf(xk, w1.y, acc[i][1][1]);
            acc[i][1][2] = fmaf(xk, w1.z, acc[i][1][2]);
            acc[i][1][3] = fmaf(xk, w1.w, acc[i][1][3]);
          }
        }
      }
    }
  }

  float4 alv0 = *(const float4*)(al + tx * 4);
  float4 arv0 = *(const float4*)(ar + tx * 4);
  float4 alv1, arv1;
  if constexpr (COLS == 128) {
    alv1 = *(const float4*)(al + 64 + tx * 4);
    arv1 = *(const float4*)(ar + 64 + tx * 4);
  }
#pragma unroll
  for (int i = 0; i < 4; ++i) {
    int r = r0 + ty * 4 + i;
    bool ok = r < N;
    float4 o0 = make_float4(acc[i][0][0], acc[i][0][1], acc[i][0][2], acc[i][0][3]);
    float pl = o0.x * alv0.x + o0.y * alv0.y + o0.z * alv0.z + o0.w * alv0.w;
    float pr = o0.x * arv0.x + o0.y * arv0.y + o0.z * arv0.z + o0.w * arv0.w;
    if (ok) *(float4*)(&H[(size_t)r * COLS + tx * 4]) = o0;
    if constexpr (COLS == 128) {
      float4 o1 = make_float4(acc[i][1][0], acc[i][1][1], acc[i][1][2], acc[i][1][3]);
      pl += o1.x * alv1.x + o1.y * alv1.y + o1.z * alv1.z + o1.w * alv1.w;
      pr += o1.x * arv1.x + o1.y * arv1.y + o1.z * arv1.z + o1.w * arv1.w;
      if (ok) *(float4*)(&H[(size_t)r * COLS + 64 + tx * 4]) = o1;
    }
#pragma unroll
    for (int off = 1; off < 16; off <<= 1) {
      pl += __shfl_xor(pl, off);
      pr += __shfl_xor(pr, off);
    }
    if (ok && tx == 0) {
      hl[r] = pl;
      hr[r] = pr;
    }
  }
}

// ---------------- per-node attention + aggregation (online softmax) ----------
// One wave per destination node, split into 4 groups x 16 lanes.
// Each group processes one incoming edge per iteration (4 edges/wave-iter);
// lane l of a group owns elements [l*EPL, l*EPL+EPL) of the feature vector.
// Per-group online softmax state, merged across groups at the end.
template <int COLS, bool LAST>
__global__ __launch_bounds__(256) void node_kernel(
    const float* __restrict__ H, const float* __restrict__ hl,
    const float* __restrict__ hr, const int* __restrict__ rowptr,
    const int* __restrict__ csr_src, const float* __restrict__ b,
    float* __restrict__ OUT, int N) {
  constexpr int EPL = COLS / 16;  // elements per lane: 8 (COLS=128) or 4 (COLS=64)
  int node = blockIdx.x * 4 + (threadIdx.x >> 6);
  if (node >= N) return;
  const int lane = threadIdx.x & 63;
  const int g = lane >> 4;   // group 0..3
  const int l = lane & 15;   // lane within group

  // h_dst fragment (same mapping in every group)
  float hi[EPL];
  {
    const float* hp = H + (size_t)node * COLS + l * EPL;
    *(float4*)&hi[0] = *(const float4*)hp;
    if constexpr (EPL == 8) *(float4*)&hi[4] = *(const float4*)(hp + 4);
  }
  const float hri = hr[node];
  const int start = rowptr[node], end = rowptr[node + 1];

  float m = -INFINITY, sumw = 0.f;
  float acc[EPL];
#pragma unroll
  for (int j = 0; j < EPL; ++j) acc[j] = 0.f;

  int e = start + g;
  int s;
  float hls;
  float hv[EPL];
  if (e < end) {  // group-uniform condition
    s = csr_src[e];
    hls = hl[s];
    const float* hp = H + (size_t)s * COLS + l * EPL;
    *(float4*)&hv[0] = *(const float4*)hp;
    if constexpr (EPL == 8) *(float4*)&hv[4] = *(const float4*)(hp + 4);
  }

  for (; e < end; e += 4) {
    float ch[EPL];
#pragma unroll
    for (int j = 0; j < EPL; ++j) ch[j] = hv[j];
    const float chl = hls;
    int en = e + 4;
    if (en < end) {  // prefetch next edge of this group
      s = csr_src[en];
      hls = hl[s];
      const float* hp = H + (size_t)s * COLS + l * EPL;
      *(float4*)&hv[0] = *(const float4*)hp;
      if constexpr (EPL == 8) *(float4*)&hv[4] = *(const float4*)(hp + 4);
    }
    // MX dot over this group's 16 lanes
    float d = 0.f;
#pragma unroll
    for (int j = 0; j < EPL; ++j) d = fmaf(hi[j], ch[j], d);
#pragma unroll
    for (int off = 1; off < 16; off <<= 1) d += __shfl_xor(d, off);
    float gate = 1.f / (1.f + __expf(-d));
    float a = (chl + hri) * gate;
    a = (a >= 0.f) ? a : 0.2f * a;
    // branchless online-softmax update (group-local state)
    float mn = fmaxf(m, a);
    float sc = __expf(m - mn);  // first iter: exp(-inf)=0
    float w = __expf(a - mn);
    sumw = fmaf(sumw, sc, w);
#pragma unroll
    for (int j = 0; j < EPL; ++j) acc[j] = fmaf(acc[j], sc, w * ch[j]);
    m = mn;
  }

  // merge the 4 groups (butterfly over lanes 16, 32 -> result in all lanes)
  float mAll = m;
  mAll = fmaxf(mAll, __shfl_xor(mAll, 16));
  mAll = fmaxf(mAll, __shfl_xor(mAll, 32));
  float sc = __expf(m - mAll);  // empty group: exp(-inf - mAll) = 0
  float sw = sumw * sc;
  sw += __shfl_xor(sw, 16);
  sw += __shfl_xor(sw, 32);
#pragma unroll
  for (int j = 0; j < EPL; ++j) {
    float t = acc[j] * sc;
    t += __shfl_xor(t, 16);
    t += __shfl_xor(t, 32);
    acc[j] = t;
  }
  const float inv = 1.f / (sw + 1e-16f);

  if constexpr (LAST) {
    // COLS == 64: 16 lanes x 4 values; all groups identical -> group 0 stores
    float o[4];
#pragma unroll
    for (int j = 0; j < 4; ++j)
      o[j] = fmaxf(acc[j] * inv + b[l * 4 + j], 0.f);
    float mx = fmaxf(fmaxf(o[0], o[1]), fmaxf(o[2], o[3]));
#pragma unroll
    for (int off = 1; off < 16; off <<= 1) mx = fmaxf(mx, __shfl_xor(mx, off));
    float es = __expf(o[0] - mx) + __expf(o[1] - mx) + __expf(o[2] - mx) + __expf(o[3] - mx);
#pragma unroll
    for (int off = 1; off < 16; off <<= 1) es += __shfl_xor(es, off);
    float ls = logf(es);
    if (g == 0) {
      float4 ov = make_float4(o[0] - mx - ls, o[1] - mx - ls, o[2] - mx - ls, o[3] - mx - ls);
      *(float4*)(&OUT[(size_t)node * 64 + l * 4]) = ov;
    }
  } else {
    // COLS == 128: groups 0,1 each store one float4 half of the lane's 8 elems
    if (g < 2) {
      float4 ov;
      ov.x = fmaxf(acc[g * 4 + 0] * inv + b[l * 8 + g * 4 + 0], 0.f);
      ov.y = fmaxf(acc[g * 4 + 1] * inv + b[l * 8 + g * 4 + 1], 0.f);
      ov.z = fmaxf(acc[g * 4 + 2] * inv + b[l * 8 + g * 4 + 2], 0.f);
      ov.w = fmaxf(acc[g * 4 + 3] * inv + b[l * 8 + g * 4 + 3], 0.f);
      *(float4*)(&OUT[(size_t)node * 128 + l * 8 + g * 4]) = ov;
    }
  }
}

// ---------------- launch ----------------
extern "C" void kernel_launch(void* const* d_in, const int* in_sizes, int n_in,
                              void* d_out, int out_size, void* d_ws, size_t ws_size,
                              hipStream_t stream) {
  const float* x = (const float*)d_in[0];
  const int* ei = (const int*)d_in[1];
  const float* W0 = (const float*)d_in[2];
  const float* al0 = (const float*)d_in[3];
  const float* ar0 = (const float*)d_in[4];
  const float* b0 = (const float*)d_in[5];
  const float* W1 = (const float*)d_in[6];
  const float* al1 = (const float*)d_in[7];
  const float* ar1 = (const float*)d_in[8];
  const float* b1 = (const float*)d_in[9];
  const float* W2 = (const float*)d_in[10];
  const float* al2 = (const float*)d_in[11];
  const float* ar2 = (const float*)d_in[12];
  const float* b2 = (const float*)d_in[13];

  const int N = in_sizes[0] / 128;  // 50000
  const int E = in_sizes[1] / 2;    // 640000
  const int ETOT = E + N;

  char* p = (char*)d_ws;
  auto carve = [&](size_t bytes) {
    void* r = (void*)p;
    p += (bytes + 255) & ~(size_t)255;
    return r;
  };
  float* hA = (float*)carve((size_t)N * 128 * sizeof(float));
  float* hB = (float*)carve((size_t)N * 128 * sizeof(float));
  float* hl = (float*)carve((size_t)N * sizeof(float));
  float* hr = (float*)carve((size_t)N * sizeof(float));
  int* counts = (int*)carve((size_t)N * sizeof(int));
  int* excl = (int*)carve((size_t)N * sizeof(int));
  int* bsums = (int*)carve(1024 * sizeof(int));
  int* rowptr = (int*)carve((size_t)(N + 1) * sizeof(int));
  int* cursor = (int*)carve((size_t)(N + 1) * sizeof(int));
  int* csr_src = (int*)carve((size_t)ETOT * sizeof(int));

  hipMemsetAsync(counts, 0, (size_t)N * sizeof(int), stream);
  {
    int nb = (ETOT + 255) / 256;
    histo_kernel<<<nb, 256, 0, stream>>>(ei, E, N, counts);
  }
  int nbs = (N + 255) / 256;
  scan1_kernel<<<nbs, 256, 0, stream>>>(counts, excl, bsums, N);
  scan2_kernel<<<1, 256, 0, stream>>>(bsums, nbs);
  scan3_kernel<<<(N + 256) / 256 + 1, 256, 0, stream>>>(excl, bsums, rowptr, cursor, N, ETOT);
  {
    int nb = (ETOT + 255) / 256;
    scatter_kernel<<<nb, 256, 0, stream>>>(ei, E, N, cursor, csr_src);
  }

  const int gemm_grid = (N + 63) / 64;
  const int node_grid = (N + 3) / 4;

  gemm_kernel<128><<<gemm_grid, 256, 0, stream>>>(x, W0, al0, ar0, hA, hl, hr, N);
  node_kernel<128, false><<<node_grid, 256, 0, stream>>>(hA, hl, hr, rowptr, csr_src, b0, hB, N);

  gemm_kernel<128><<<gemm_grid, 256, 0, stream>>>(hB, W1, al1, ar1, hA, hl, hr, N);
  node_kernel<128, false><<<node_grid, 256, 0, stream>>>(hA, hl, hr, rowptr, csr_src, b1, hB, N);

  gemm_kernel<64><<<gemm_grid, 256, 0, stream>>>(hB, W2, al2, ar2, hA, hl, hr, N);
  node_kernel<64, true><<<node_grid, 256, 0, stream>>>(hA, hl, hr, rowptr, csr_src, b2,
                                                       (float*)d_out, N);
}